// Round 10
// baseline (377.371 us; speedup 1.0000x reference)
//
#include <hip/hip_runtime.h>

// RandomProjectionQuantizer: out[n] = argmin_j || x_n @ W^T - c_j ||^2
//   == argmin_j ( c2[j] - 2 * t_n . c_j )
//
// R10: dist kernel occupancy fix. R9 counters: MfmaUtil 37.5, VALU 29.5,
// LDS 22%, HBM 10% -> nothing saturated, latency-bound at 1.75 blocks/CU
// (LDS 66KB). Now BK=32 with packed [hi|lo] 128B LDS rows -> 34KB/block ->
// 4 blocks/CU. Same swizzle family (chunk ^= row&7, 16-lane phases conflict-
// free). cvt merged into c2 (one CB pass). 3-term fp16 split unchanged.

#define D_IN      320
#define CODE_DIM  512
#define NUM_CODES 8192
#define N_ROWS    8192

typedef _Float16 f16;
typedef __attribute__((ext_vector_type(4))) _Float16 f16x4;
typedef __attribute__((ext_vector_type(8))) _Float16 f16x8;
typedef __attribute__((ext_vector_type(4))) float    f32x4;

// ------------------------------------- c2 + codebook hi/lo split (one pass)
__global__ __launch_bounds__(256) void c2cvt_kernel(const float* __restrict__ cb,
                                                    float* __restrict__ c2,
                                                    f16* __restrict__ hi,
                                                    f16* __restrict__ lo) {
    int wave = blockIdx.x * 4 + (threadIdx.x >> 6);
    int lane = threadIdx.x & 63;
    const float* row = cb + (size_t)wave * CODE_DIM;
    float4 v0 = *(const float4*)(row + lane * 8);
    float4 v1 = *(const float4*)(row + lane * 8 + 4);
    float vv[8] = {v0.x, v0.y, v0.z, v0.w, v1.x, v1.y, v1.z, v1.w};
    f16x8 hv, lv;
    float s = 0.f;
#pragma unroll
    for (int i = 0; i < 8; ++i) {
        float v = vv[i];
        s += v * v;
        f16 h = (f16)v;
        hv[i] = h;
        lv[i] = (f16)(v - (float)h);
    }
    *(f16x8*)(hi + (size_t)wave * CODE_DIM + lane * 8) = hv;
    *(f16x8*)(lo + (size_t)wave * CODE_DIM + lane * 8) = lv;
#pragma unroll
    for (int off = 32; off > 0; off >>= 1) s += __shfl_down(s, off, 64);
    if (lane == 0) c2[wave] = s;
}

// ------------------------------------------------------------ projection
// T = X @ W^T : M=8192, N=512, K=320. Epilogue writes hi/lo fp16 planes.
#define PB_M 64
#define PB_N 64
#define PB_K 32
#define PLD  (PB_K + 4)

__global__ __launch_bounds__(256) void proj_kernel(const float* __restrict__ X,
                                                   const float* __restrict__ W,
                                                   f16* __restrict__ Thi,
                                                   f16* __restrict__ Tlo) {
    __shared__ float Xs[PB_M][PLD];
    __shared__ float Wsh[PB_N][PLD];
    const int bm = blockIdx.x;
    const int bn = blockIdx.y;
    const int tid = threadIdx.x;
    const int tx = tid & 15;
    const int ty = tid >> 4;
    float acc[4][4] = {};
    for (int kc = 0; kc < D_IN; kc += PB_K) {
#pragma unroll
        for (int it = 0; it < 2; ++it) {
            int idx = tid + 256 * it;
            int r   = idx >> 3;
            int kp  = (idx & 7) * 4;
            *(float4*)&Xs[r][kp] =
                *(const float4*)(X + (size_t)(bm * PB_M + r) * D_IN + kc + kp);
            *(float4*)&Wsh[r][kp] =
                *(const float4*)(W + (size_t)(bn * PB_N + r) * D_IN + kc + kp);
        }
        __syncthreads();
#pragma unroll
        for (int kk = 0; kk < PB_K; ++kk) {
            float a[4], b[4];
#pragma unroll
            for (int i = 0; i < 4; ++i) a[i] = Xs[ty + 16 * i][kk];
#pragma unroll
            for (int j = 0; j < 4; ++j) b[j] = Wsh[tx + 16 * j][kk];
#pragma unroll
            for (int i = 0; i < 4; ++i)
#pragma unroll
                for (int j = 0; j < 4; ++j) acc[i][j] += a[i] * b[j];
        }
        __syncthreads();
    }
#pragma unroll
    for (int i = 0; i < 4; ++i)
#pragma unroll
        for (int j = 0; j < 4; ++j) {
            size_t idx = (size_t)(bm * PB_M + ty + 16 * i) * CODE_DIM +
                         bn * PB_N + tx + 16 * j;
            float v = acc[i][j];
            f16  h = (f16)v;
            Thi[idx] = h;
            Tlo[idx] = (f16)(v - (float)h);
        }
}

// -------------------------------- phase A: MFMA dist + fused argmin
// Block 128x128, 4 waves (2x2), wave tile 64x64 = 4x4 mfma_f32_16x16x32_f16.
// LDS: per matrix 128 rows x 128B = [hi 4x16B | lo 4x16B], chunk ^= (row&7).
// 2048 uint4 slots total (A then B) = 32KB; +2KB reduce -> 4 blocks/CU.
#define BM 128
#define BN 128
#define BK 32

__global__ __launch_bounds__(256) void dist_mfma_kernel(
        const f16* __restrict__ Thi, const f16* __restrict__ Tlo,
        const f16* __restrict__ Chi, const f16* __restrict__ Clo,
        const float* __restrict__ c2, float2* __restrict__ part) {
    __shared__ uint4 lds4[2048];          // 32 KB: slots [0,1024)=A, [1024,2048)=B
    __shared__ float red_v[BM][2];
    __shared__ int   red_i[BM][2];

    const int tid = threadIdx.x;
    const int l   = tid & 63;
    const int w   = tid >> 6;        // 0..3
    const int wr  = w >> 1;          // wave row 0..1
    const int wc  = w & 1;           // wave col 0..1
    const int rb  = blockIdx.y * BM;
    const int cbase = blockIdx.x * BN;
    const int cgrp = l >> 4;         // k-chunk 0..3 (16B = 8 f16 along K)

    f32x4 acc[4][4];
#pragma unroll
    for (int i = 0; i < 4; ++i)
#pragma unroll
        for (int j = 0; j < 4; ++j) acc[i][j] = (f32x4){0.f, 0.f, 0.f, 0.f};

    for (int kc = 0; kc < CODE_DIM; kc += BK) {
        __syncthreads();   // previous compute done before LDS overwrite
        // stage: 2048 slots, 8 per thread. slot -> mat|row|chunk; chunk 0..3
        // = hi k-seg, 4..7 = lo k-seg; stored at chunk ^ (row&7).
#pragma unroll
        for (int it = 0; it < 8; ++it) {
            int slot = it * 256 + tid;
            int mat  = slot >> 10;
            int sm   = slot & 1023;
            int r    = sm >> 3;
            int c    = sm & 7;
            const f16* src = mat ? (c < 4 ? Chi : Clo) : (c < 4 ? Thi : Tlo);
            int row_g = (mat ? cbase : rb) + r;
            uint4 v = *(const uint4*)(src + (size_t)row_g * CODE_DIM + kc +
                                      (c & 3) * 8);
            lds4[(mat << 10) + (r << 3) + (c ^ (r & 7))] = v;
        }
        __syncthreads();
        f16x8 ah[4], al[4], bh[4], bl[4];
#pragma unroll
        for (int i = 0; i < 4; ++i) {
            int r = wr * 64 + i * 16 + (l & 15);
            int s = r & 7;
            ah[i] = *(const f16x8*)&lds4[(r << 3) + (cgrp ^ s)];
            al[i] = *(const f16x8*)&lds4[(r << 3) + ((4 + cgrp) ^ s)];
        }
#pragma unroll
        for (int j = 0; j < 4; ++j) {
            int r = wc * 64 + j * 16 + (l & 15);
            int s = r & 7;
            bh[j] = *(const f16x8*)&lds4[1024 + (r << 3) + (cgrp ^ s)];
            bl[j] = *(const f16x8*)&lds4[1024 + (r << 3) + ((4 + cgrp) ^ s)];
        }
#pragma unroll
        for (int i = 0; i < 4; ++i)
#pragma unroll
            for (int j = 0; j < 4; ++j) {
                acc[i][j] = __builtin_amdgcn_mfma_f32_16x16x32_f16(
                    ah[i], bh[j], acc[i][j], 0, 0, 0);
                acc[i][j] = __builtin_amdgcn_mfma_f32_16x16x32_f16(
                    ah[i], bl[j], acc[i][j], 0, 0, 0);
                acc[i][j] = __builtin_amdgcn_mfma_f32_16x16x32_f16(
                    al[i], bh[j], acc[i][j], 0, 0, 0);
            }
    }

    // epilogue: C/D layout (m89/m91): row=(l>>4)*4+p, col=l&15.
    // per-lane argmin over j (codes ascending), butterfly over 16 lanes,
    // exact (val,idx) first-index tie-break.
#pragma unroll
    for (int i = 0; i < 4; ++i) {
        float bvv[4];
        int   bii[4];
#pragma unroll
        for (int p = 0; p < 4; ++p) { bvv[p] = 3.4e38f; bii[p] = 0x7fffffff; }
#pragma unroll
        for (int j = 0; j < 4; ++j) {
            int   code = cbase + wc * 64 + j * 16 + (l & 15);
            float cc   = c2[code];
#pragma unroll
            for (int p = 0; p < 4; ++p) {
                float s = cc - 2.0f * acc[i][j][p];
                if (s < bvv[p]) { bvv[p] = s; bii[p] = code; }
            }
        }
#pragma unroll
        for (int off = 1; off < 16; off <<= 1) {
#pragma unroll
            for (int p = 0; p < 4; ++p) {
                float ov = __shfl_xor(bvv[p], off, 64);
                int   oi = __shfl_xor(bii[p], off, 64);
                if (ov < bvv[p] || (ov == bvv[p] && oi < bii[p])) {
                    bvv[p] = ov; bii[p] = oi;
                }
            }
        }
        if ((l & 15) == 0) {
#pragma unroll
            for (int p = 0; p < 4; ++p) {
                int rloc = wr * 64 + i * 16 + (l >> 4) * 4 + p;
                red_v[rloc][wc] = bvv[p];
                red_i[rloc][wc] = bii[p];
            }
        }
    }
    __syncthreads();
    if (tid < BM) {
        float v0 = red_v[tid][0], v1 = red_v[tid][1];
        int   i0 = red_i[tid][0], i1 = red_i[tid][1];
        bool  t1 = (v1 < v0) || (v1 == v0 && i1 < i0);
        part[(size_t)(rb + tid) * (NUM_CODES / BN) + blockIdx.x] =
            make_float2(t1 ? v1 : v0, __int_as_float(t1 ? i1 : i0));
    }
}

// ---------------------------- phase B: reduce 64 partials/row, wave per row
__global__ __launch_bounds__(256) void argmin_reduce_kernel(
        const float2* __restrict__ part, int* __restrict__ out) {
    int row  = blockIdx.x * 4 + (threadIdx.x >> 6);
    int lane = threadIdx.x & 63;
    float2 p = part[(size_t)row * 64 + lane];
    float bv = p.x;
    int   bi = __float_as_int(p.y);
#pragma unroll
    for (int off = 32; off > 0; off >>= 1) {
        float ov = __shfl_down(bv, off, 64);
        int   oi = __shfl_down(bi, off, 64);
        if (ov < bv || (ov == bv && oi < bi)) { bv = ov; bi = oi; }
    }
    if (lane == 0) out[row] = bi;
}

// ---------------------------------------------------------------- launch
extern "C" void kernel_launch(void* const* d_in, const int* in_sizes, int n_in,
                              void* d_out, int out_size, void* d_ws, size_t ws_size,
                              hipStream_t stream) {
    const float* X  = (const float*)d_in[0];   // (8192, 320)
    // d_in[1]: mask_time_indices — statically all-ones -> unused
    const float* W  = (const float*)d_in[2];   // (512, 320)
    const float* CB = (const float*)d_in[3];   // (8192, 512)
    int* out = (int*)d_out;                    // (8192,) int32

    const size_t PLANE = (size_t)N_ROWS * CODE_DIM * sizeof(f16);  // 8 MB
    char* ws = (char*)d_ws;
    f16*    Thi = (f16*)(ws);
    f16*    Tlo = (f16*)(ws + PLANE);
    f16*    Chi = (f16*)(ws + 2 * PLANE);
    f16*    Clo = (f16*)(ws + 3 * PLANE);
    float*  c2  = (float*)(ws + 4 * PLANE);                        // 32 KB
    float2* part = (float2*)(ws + 4 * PLANE + NUM_CODES * sizeof(float)); // 4 MB

    c2cvt_kernel<<<NUM_CODES / 4, 256, 0, stream>>>(CB, c2, Chi, Clo);

    dim3 pgrid(N_ROWS / PB_M, CODE_DIM / PB_N);
    proj_kernel<<<pgrid, 256, 0, stream>>>(X, W, Thi, Tlo);

    dim3 dgrid(NUM_CODES / BN, N_ROWS / BM);   // (64, 64)
    dist_mfma_kernel<<<dgrid, 256, 0, stream>>>(Thi, Tlo, Chi, Clo, c2, part);

    argmin_reduce_kernel<<<N_ROWS / 4, 256, 0, stream>>>(part, out);
}